// Round 2
// baseline (187.280 us; speedup 1.0000x reference)
//
#include <hip/hip_runtime.h>
#include <math.h>

#define HF 37
#define WF 50
#define CC 512
#define POOLD 7
#define SAMPD 14

__device__ __forceinline__ float4 lerp4(float4 a, float4 b, float t) {
    float4 r;
    r.x = a.x + t * (b.x - a.x);
    r.y = a.y + t * (b.y - a.y);
    r.z = a.z + t * (b.z - a.z);
    r.w = a.w + t * (b.w - a.w);
    return r;
}

__device__ __forceinline__ float4 max4(float4 a, float4 b) {
    float4 r;
    r.x = fmaxf(a.x, b.x);
    r.y = fmaxf(a.y, b.y);
    r.z = fmaxf(a.z, b.z);
    r.w = fmaxf(a.w, b.w);
    return r;
}

// One block per (roi, pooled_row). 128 threads * float4 = 512 channels.
// Each thread computes all 7 px bins for its channel quad.
// Column register-cache exploits monotone xs across the 14 sample columns.
__global__ __launch_bounds__(128) void roipool_kernel(
    const float* __restrict__ feat,   // [HF, WF, CC]
    const float* __restrict__ rois,   // [N, 4] (x1,y1,x2,y2)
    const int*   __restrict__ im_size,// [2] (h, w)
    float*       __restrict__ out,    // [N, 7, 7, CC]
    int N)
{
    int bid = blockIdx.x;
    int n   = bid / POOLD;
    int py  = bid - n * POOLD;
    if (n >= N) return;

    float h = (float)im_size[0];
    float w = (float)im_size[1];
    float bx1 = rois[4 * n + 0];
    float by1 = rois[4 * n + 1];
    float bx2 = rois[4 * n + 2];
    float by2 = rois[4 * n + 3];
    float ny1 = by1 / h, nx1 = bx1 / w;
    float ny2 = by2 / h, nx2 = bx2 / w;

    const float inv = 1.0f / (float)(SAMPD - 1);

    // --- two sample rows for this pooled row (block-uniform) ---
    float wya, wyb;
    int rowoff[4];  // element offsets of the 4 tap rows
    {
        float ty = (float)(2 * py) * inv;
        float ys = (ny1 + (ny2 - ny1) * ty) * (float)(HF - 1);
        ys = fminf(fmaxf(ys, 0.0f), (float)(HF - 1));
        float y0f = floorf(ys);
        int iy0 = (int)y0f;
        int iy1 = min(iy0 + 1, HF - 1);
        wya = ys - y0f;
        rowoff[0] = __builtin_amdgcn_readfirstlane(iy0) * (WF * CC);
        rowoff[1] = __builtin_amdgcn_readfirstlane(iy1) * (WF * CC);

        ty = (float)(2 * py + 1) * inv;
        ys = (ny1 + (ny2 - ny1) * ty) * (float)(HF - 1);
        ys = fminf(fmaxf(ys, 0.0f), (float)(HF - 1));
        y0f = floorf(ys);
        iy0 = (int)y0f;
        iy1 = min(iy0 + 1, HF - 1);
        wyb = ys - y0f;
        rowoff[2] = __builtin_amdgcn_readfirstlane(iy0) * (WF * CC);
        rowoff[3] = __builtin_amdgcn_readfirstlane(iy1) * (WF * CC);
    }

    const float* pbase = feat + (size_t)threadIdx.x * 4;

    float4 acc[POOLD];
    #pragma unroll
    for (int i = 0; i < POOLD; ++i)
        acc[i] = make_float4(-INFINITY, -INFINITY, -INFINITY, -INFINITY);

    // two-column register cache (indices are scalar/uniform)
    int ca_ix = -1, cb_ix = -1;
    float4 colA[4], colB[4];

    #pragma unroll
    for (int sx = 0; sx < SAMPD; ++sx) {
        float tx = (float)sx * inv;
        float xs = (nx1 + (nx2 - nx1) * tx) * (float)(WF - 1);
        xs = fminf(fmaxf(xs, 0.0f), (float)(WF - 1));
        float x0f = floorf(xs);
        int ix0 = __builtin_amdgcn_readfirstlane((int)x0f);
        int ix1 = __builtin_amdgcn_readfirstlane(min(ix0 + 1, WF - 1));
        float wx = xs - x0f;

        float4 a[4], b[4];

        if (ix0 == ca_ix) {
            #pragma unroll
            for (int r = 0; r < 4; ++r) a[r] = colA[r];
        } else if (ix0 == cb_ix) {
            #pragma unroll
            for (int r = 0; r < 4; ++r) a[r] = colB[r];
        } else {
            #pragma unroll
            for (int r = 0; r < 4; ++r)
                a[r] = *(const float4*)(pbase + rowoff[r] + ix0 * CC);
        }

        if (ix1 == ix0) {
            #pragma unroll
            for (int r = 0; r < 4; ++r) b[r] = a[r];
        } else if (ix1 == cb_ix) {
            #pragma unroll
            for (int r = 0; r < 4; ++r) b[r] = colB[r];
        } else {
            #pragma unroll
            for (int r = 0; r < 4; ++r)
                b[r] = *(const float4*)(pbase + rowoff[r] + ix1 * CC);
        }

        // rotate cache
        ca_ix = ix0; cb_ix = ix1;
        #pragma unroll
        for (int r = 0; r < 4; ++r) { colA[r] = a[r]; colB[r] = b[r]; }

        // horizontal lerp per tap row
        float4 h0 = lerp4(a[0], b[0], wx);
        float4 h1 = lerp4(a[1], b[1], wx);
        float4 h2 = lerp4(a[2], b[2], wx);
        float4 h3 = lerp4(a[3], b[3], wx);

        // vertical lerp for the two sample rows
        float4 va = lerp4(h0, h1, wya);
        float4 vb = lerp4(h2, h3, wyb);

        int px = sx >> 1;  // compile-time per unrolled iteration
        acc[px] = max4(acc[px], max4(va, vb));
    }

    float* obase = out + ((size_t)(n * POOLD + py) * POOLD) * CC + (size_t)threadIdx.x * 4;
    #pragma unroll
    for (int px = 0; px < POOLD; ++px)
        *(float4*)(obase + (size_t)px * CC) = acc[px];
}

extern "C" void kernel_launch(void* const* d_in, const int* in_sizes, int n_in,
                              void* d_out, int out_size, void* d_ws, size_t ws_size,
                              hipStream_t stream) {
    const float* feat    = (const float*)d_in[0];   // [1,37,50,512]
    const float* rois    = (const float*)d_in[1];   // [N,4]
    const int*   im_size = (const int*)d_in[2];     // [2]
    float* out = (float*)d_out;

    int N = in_sizes[1] / 4;
    int nblocks = N * POOLD;
    roipool_kernel<<<nblocks, 128, 0, stream>>>(feat, rois, im_size, out, N);
}

// Round 3
// 127.083 us; speedup vs baseline: 1.4737x; 1.4737x over previous
//
#include <hip/hip_runtime.h>
#include <math.h>

#define HF 37
#define WF 50
#define CC 512
#define POOLD 7
#define SAMPD 14

__device__ __forceinline__ float4 lerp4(float4 a, float4 b, float t) {
    float4 r;
    r.x = a.x + t * (b.x - a.x);
    r.y = a.y + t * (b.y - a.y);
    r.z = a.z + t * (b.z - a.z);
    r.w = a.w + t * (b.w - a.w);
    return r;
}

__device__ __forceinline__ float4 max4(float4 a, float4 b) {
    float4 r;
    r.x = fmaxf(a.x, b.x);
    r.y = fmaxf(a.y, b.y);
    r.z = fmaxf(a.z, b.z);
    r.w = fmaxf(a.w, b.w);
    return r;
}

// Load one feature column (4 tap rows) and reduce vertically -> (va, vb).
__device__ __forceinline__ void loadcol(const float* __restrict__ pbase, int col,
                                        int ro0, int ro1, int ro2, int ro3,
                                        float wya, float wyb,
                                        float4& va, float4& vb) {
    const float* p = pbase + (size_t)col * CC;
    float4 r0 = *(const float4*)(p + ro0);
    float4 r1 = *(const float4*)(p + ro1);
    float4 r2 = *(const float4*)(p + ro2);
    float4 r3 = *(const float4*)(p + ro3);
    va = lerp4(r0, r1, wya);
    vb = lerp4(r2, r3, wyb);
}

// One block per (roi, pooled_row). 128 threads * float4 = 512 channels.
// Monotone column walk with a 2-column vertically-reduced register cache.
__global__ __launch_bounds__(128, 3) void roipool_kernel(
    const float* __restrict__ feat,    // [HF, WF, CC]
    const float* __restrict__ rois,    // [N, 4] (x1,y1,x2,y2)
    const int*   __restrict__ im_size, // [2] (h, w)
    float*       __restrict__ out,     // [N, 7, 7, CC]
    int N)
{
    int bid = blockIdx.x;
    int n   = bid / POOLD;
    int py  = bid - n * POOLD;
    if (n >= N) return;

    float h = (float)im_size[0];
    float w = (float)im_size[1];
    float bx1 = rois[4 * n + 0];
    float by1 = rois[4 * n + 1];
    float bx2 = rois[4 * n + 2];
    float by2 = rois[4 * n + 3];
    float ny1 = by1 / h, nx1 = bx1 / w;
    float ny2 = by2 / h, nx2 = bx2 / w;

    const float inv = 1.0f / (float)(SAMPD - 1);

    // --- vertical taps for the two sample rows of this pooled row (uniform) ---
    float tya = (float)(2 * py) * inv;
    float tyb = (float)(2 * py + 1) * inv;
    float ysa = (ny1 + (ny2 - ny1) * tya) * (float)(HF - 1);
    float ysb = (ny1 + (ny2 - ny1) * tyb) * (float)(HF - 1);
    ysa = fminf(fmaxf(ysa, 0.0f), (float)(HF - 1));
    ysb = fminf(fmaxf(ysb, 0.0f), (float)(HF - 1));
    float y0fa = floorf(ysa);
    float y0fb = floorf(ysb);
    float wya = ysa - y0fa;
    float wyb = ysb - y0fb;
    int iya = __builtin_amdgcn_readfirstlane((int)y0fa);
    int iyb = __builtin_amdgcn_readfirstlane((int)y0fb);
    int iya1 = min(iya + 1, HF - 1);
    int iyb1 = min(iyb + 1, HF - 1);
    int ro0 = iya  * (WF * CC);
    int ro1 = iya1 * (WF * CC);
    int ro2 = iyb  * (WF * CC);
    int ro3 = iyb1 * (WF * CC);

    const float* pbase = feat + (size_t)threadIdx.x * 4;
    float* obase = out + ((size_t)(n * POOLD + py) * POOLD) * CC + (size_t)threadIdx.x * 4;

    // 2-column cache of vertically-reduced values (indices are scalar)
    int pcol = -1000, ccol = -1000;
    float4 vap, vbp, vac, vbc;
    float4 m0;

    #pragma unroll
    for (int sx = 0; sx < SAMPD; ++sx) {
        float tx = (float)sx * inv;
        float xs = (nx1 + (nx2 - nx1) * tx) * (float)(WF - 1);
        xs = fminf(fmaxf(xs, 0.0f), (float)(WF - 1));
        float x0f = floorf(xs);
        float wx = xs - x0f;
        int c0 = __builtin_amdgcn_readfirstlane((int)x0f);
        int c1 = min(c0 + 1, WF - 1);

        if (c0 == ccol) {
            // shift cur -> prev, load one new column
            pcol = ccol; vap = vac; vbp = vbc;
            loadcol(pbase, c1, ro0, ro1, ro2, ro3, wya, wyb, vac, vbc);
            ccol = c1;
        } else if (c0 != pcol) {
            // cache miss on both columns (includes first iteration)
            loadcol(pbase, c0, ro0, ro1, ro2, ro3, wya, wyb, vap, vbp);
            pcol = c0;
            loadcol(pbase, c1, ro0, ro1, ro2, ro3, wya, wyb, vac, vbc);
            ccol = c1;
        }
        // else: c0 == pcol, both columns already cached

        // horizontal lerp for the two sample rows, then max
        float4 sa = lerp4(vap, vac, wx);
        float4 sb = lerp4(vbp, vbc, wx);
        float4 mm = max4(sa, sb);

        if (sx & 1) {
            float4 r = max4(m0, mm);
            *(float4*)(obase + (size_t)(sx >> 1) * CC) = r;
        } else {
            m0 = mm;
        }
    }
}

extern "C" void kernel_launch(void* const* d_in, const int* in_sizes, int n_in,
                              void* d_out, int out_size, void* d_ws, size_t ws_size,
                              hipStream_t stream) {
    const float* feat    = (const float*)d_in[0];   // [1,37,50,512]
    const float* rois    = (const float*)d_in[1];   // [N,4]
    const int*   im_size = (const int*)d_in[2];     // [2]
    float* out = (float*)d_out;

    int N = in_sizes[1] / 4;
    int nblocks = N * POOLD;
    roipool_kernel<<<nblocks, 128, 0, stream>>>(feat, rois, im_size, out, N);
}

// Round 5
// 126.829 us; speedup vs baseline: 1.4766x; 1.0020x over previous
//
#include <hip/hip_runtime.h>
#include <math.h>

#define HF 37
#define WF 50
#define CC 512
#define POOLD 7
#define SAMPD 14

typedef float nfloat4 __attribute__((ext_vector_type(4)));

__device__ __forceinline__ float4 lerp4(float4 a, float4 b, float t) {
    float4 r;
    r.x = a.x + t * (b.x - a.x);
    r.y = a.y + t * (b.y - a.y);
    r.z = a.z + t * (b.z - a.z);
    r.w = a.w + t * (b.w - a.w);
    return r;
}

__device__ __forceinline__ float4 max4(float4 a, float4 b) {
    float4 r;
    r.x = fmaxf(a.x, b.x);
    r.y = fmaxf(a.y, b.y);
    r.z = fmaxf(a.z, b.z);
    r.w = fmaxf(a.w, b.w);
    return r;
}

__device__ __forceinline__ void store_nt4(float* p, float4 v) {
    nfloat4 nv;
    nv.x = v.x; nv.y = v.y; nv.z = v.z; nv.w = v.w;
    __builtin_nontemporal_store(nv, (nfloat4*)p);
}

// Load one feature column and vertically reduce to the two sample rows.
// RC = row-sharing case (fixed per block): 0 -> both samples share the same
// row pair (2 loads); 1 -> they share the middle row (3 loads); 2 -> general
// (4 loads).
template <int RC>
__device__ __forceinline__ void loadcol(const float* __restrict__ pbase, int col,
                                        int ro0, int ro1, int ro2, int ro3,
                                        float wya, float wyb,
                                        float4& va, float4& vb) {
    const float* p = pbase + (size_t)col * CC;
    if (RC == 0) {
        float4 rA = *(const float4*)(p + ro0);
        float4 rB = *(const float4*)(p + ro1);
        va = lerp4(rA, rB, wya);
        vb = lerp4(rA, rB, wyb);
    } else if (RC == 1) {
        float4 rA = *(const float4*)(p + ro0);
        float4 rB = *(const float4*)(p + ro1);
        float4 rC = *(const float4*)(p + ro3);
        va = lerp4(rA, rB, wya);
        vb = lerp4(rB, rC, wyb);
    } else {
        float4 r0 = *(const float4*)(p + ro0);
        float4 r1 = *(const float4*)(p + ro1);
        float4 r2 = *(const float4*)(p + ro2);
        float4 r3 = *(const float4*)(p + ro3);
        va = lerp4(r0, r1, wya);
        vb = lerp4(r2, r3, wyb);
    }
}

template <int RC>
__device__ __forceinline__ void run_row(const float* __restrict__ pbase,
                                        float* __restrict__ obase,
                                        float nx1, float nx2,
                                        int ro0, int ro1, int ro2, int ro3,
                                        float wya, float wyb) {
    const float inv = 1.0f / (float)(SAMPD - 1);

    int pcol = -1000, ccol = -1000;
    float4 vap, vbp, vac, vbc;
    float4 m0;

    #pragma unroll
    for (int sx = 0; sx < SAMPD; ++sx) {
        float tx = (float)sx * inv;
        float xs = (nx1 + (nx2 - nx1) * tx) * (float)(WF - 1);
        xs = fminf(fmaxf(xs, 0.0f), (float)(WF - 1));
        float x0f = floorf(xs);
        float wx = xs - x0f;
        int c0 = __builtin_amdgcn_readfirstlane((int)x0f);
        int c1 = min(c0 + 1, WF - 1);

        if (c0 == ccol) {
            pcol = ccol; vap = vac; vbp = vbc;
            loadcol<RC>(pbase, c1, ro0, ro1, ro2, ro3, wya, wyb, vac, vbc);
            ccol = c1;
        } else if (c0 != pcol) {
            loadcol<RC>(pbase, c0, ro0, ro1, ro2, ro3, wya, wyb, vap, vbp);
            pcol = c0;
            loadcol<RC>(pbase, c1, ro0, ro1, ro2, ro3, wya, wyb, vac, vbc);
            ccol = c1;
        }

        float4 sa = lerp4(vap, vac, wx);
        float4 sb = lerp4(vbp, vbc, wx);
        float4 mm = max4(sa, sb);

        if (sx & 1) {
            float4 r = max4(m0, mm);
            store_nt4(obase + (size_t)(sx >> 1) * CC, r);
        } else {
            m0 = mm;
        }
    }
}

// One block per (roi, pooled_row). 128 threads * float4 = 512 channels.
__global__ __launch_bounds__(128, 3) void roipool_kernel(
    const float* __restrict__ feat,    // [HF, WF, CC]
    const float* __restrict__ rois,    // [N, 4] (x1,y1,x2,y2)
    const int*   __restrict__ im_size, // [2] (h, w)
    float*       __restrict__ out,     // [N, 7, 7, CC]
    int N)
{
    int bid = blockIdx.x;
    int n   = bid / POOLD;
    int py  = bid - n * POOLD;
    if (n >= N) return;

    float h = (float)im_size[0];
    float w = (float)im_size[1];
    float bx1 = rois[4 * n + 0];
    float by1 = rois[4 * n + 1];
    float bx2 = rois[4 * n + 2];
    float by2 = rois[4 * n + 3];
    float ny1 = by1 / h, nx1 = bx1 / w;
    float ny2 = by2 / h, nx2 = bx2 / w;

    const float inv = 1.0f / (float)(SAMPD - 1);

    // --- vertical taps for the two sample rows of this pooled row (uniform) ---
    float tya = (float)(2 * py) * inv;
    float tyb = (float)(2 * py + 1) * inv;
    float ysa = (ny1 + (ny2 - ny1) * tya) * (float)(HF - 1);
    float ysb = (ny1 + (ny2 - ny1) * tyb) * (float)(HF - 1);
    ysa = fminf(fmaxf(ysa, 0.0f), (float)(HF - 1));
    ysb = fminf(fmaxf(ysb, 0.0f), (float)(HF - 1));
    float y0fa = floorf(ysa);
    float y0fb = floorf(ysb);
    float wya = ysa - y0fa;
    float wyb = ysb - y0fb;
    int iya = __builtin_amdgcn_readfirstlane((int)y0fa);
    int iyb = __builtin_amdgcn_readfirstlane((int)y0fb);
    int iya1 = min(iya + 1, HF - 1);
    int iyb1 = min(iyb + 1, HF - 1);
    int ro0 = iya  * (WF * CC);
    int ro1 = iya1 * (WF * CC);
    int ro2 = iyb  * (WF * CC);
    int ro3 = iyb1 * (WF * CC);

    const float* pbase = feat + (size_t)threadIdx.x * 4;
    float* obase = out + ((size_t)(n * POOLD + py) * POOLD) * CC + (size_t)threadIdx.x * 4;

    // Row-sharing case is fixed for the whole block -> one scalar dispatch.
    if (ro2 == ro0) {
        run_row<0>(pbase, obase, nx1, nx2, ro0, ro1, ro2, ro3, wya, wyb);
    } else if (ro2 == ro1) {
        run_row<1>(pbase, obase, nx1, nx2, ro0, ro1, ro2, ro3, wya, wyb);
    } else {
        run_row<2>(pbase, obase, nx1, nx2, ro0, ro1, ro2, ro3, wya, wyb);
    }
}

extern "C" void kernel_launch(void* const* d_in, const int* in_sizes, int n_in,
                              void* d_out, int out_size, void* d_ws, size_t ws_size,
                              hipStream_t stream) {
    const float* feat    = (const float*)d_in[0];   // [1,37,50,512]
    const float* rois    = (const float*)d_in[1];   // [N,4]
    const int*   im_size = (const int*)d_in[2];     // [2]
    float* out = (float*)d_out;

    int N = in_sizes[1] / 4;
    int nblocks = N * POOLD;
    roipool_kernel<<<nblocks, 128, 0, stream>>>(feat, rois, im_size, out, N);
}

// Round 6
// 124.333 us; speedup vs baseline: 1.5063x; 1.0201x over previous
//
#include <hip/hip_runtime.h>
#include <math.h>

#define HF 37
#define WF 50
#define CC 512
#define POOLD 7
#define SAMPD 14

typedef float nfloat4 __attribute__((ext_vector_type(4)));

__device__ __forceinline__ float4 lerp4(float4 a, float4 b, float t) {
    float4 r;
    r.x = a.x + t * (b.x - a.x);
    r.y = a.y + t * (b.y - a.y);
    r.z = a.z + t * (b.z - a.z);
    r.w = a.w + t * (b.w - a.w);
    return r;
}

__device__ __forceinline__ float4 max4(float4 a, float4 b) {
    float4 r;
    r.x = fmaxf(a.x, b.x);
    r.y = fmaxf(a.y, b.y);
    r.z = fmaxf(a.z, b.z);
    r.w = fmaxf(a.w, b.w);
    return r;
}

__device__ __forceinline__ void store_nt4(float* p, float4 v) {
    nfloat4 nv;
    nv.x = v.x; nv.y = v.y; nv.z = v.z; nv.w = v.w;
    __builtin_nontemporal_store(nv, (nfloat4*)p);
}

// Load one feature column and vertically reduce to the two sample rows.
// RC (fixed per block): 0 -> both samples use the same row pair (2 loads);
// 1 -> middle row shared (3 loads); 2 -> general (4 loads).
template <int RC>
__device__ __forceinline__ void loadcol(const float* __restrict__ pbase, int col,
                                        int ro0, int ro1, int ro2, int ro3,
                                        float wya, float wyb,
                                        float4& va, float4& vb) {
    const float* p = pbase + (size_t)col * CC;
    if (RC == 0) {
        float4 rA = *(const float4*)(p + ro0);
        float4 rB = *(const float4*)(p + ro1);
        va = lerp4(rA, rB, wya);
        vb = lerp4(rA, rB, wyb);
    } else if (RC == 1) {
        float4 rA = *(const float4*)(p + ro0);
        float4 rB = *(const float4*)(p + ro1);
        float4 rC = *(const float4*)(p + ro3);
        va = lerp4(rA, rB, wya);
        vb = lerp4(rB, rC, wyb);
    } else {
        float4 r0 = *(const float4*)(p + ro0);
        float4 r1 = *(const float4*)(p + ro1);
        float4 r2 = *(const float4*)(p + ro2);
        float4 r3 = *(const float4*)(p + ro3);
        va = lerp4(r0, r1, wya);
        vb = lerp4(r2, r3, wyb);
    }
}

template <int RC>
__device__ __forceinline__ void run_row(const float* __restrict__ pbase,
                                        float* __restrict__ obase,
                                        float nx1, float nx2,
                                        int ro0, int ro1, int ro2, int ro3,
                                        float wya, float wyb) {
    const float inv = 1.0f / (float)(SAMPD - 1);

    int pcol = -1000, ccol = -1000;
    float4 vap, vbp, vac, vbc;
    float4 m0 = make_float4(-INFINITY, -INFINITY, -INFINITY, -INFINITY);

    // ROLLED loop: keeps live state ~1 iteration -> low VGPR -> high occupancy.
    #pragma unroll 1
    for (int sx = 0; sx < SAMPD; ++sx) {
        float tx = (float)sx * inv;
        float xs = (nx1 + (nx2 - nx1) * tx) * (float)(WF - 1);
        xs = fminf(fmaxf(xs, 0.0f), (float)(WF - 1));
        float x0f = floorf(xs);
        float wx = xs - x0f;
        int c0 = __builtin_amdgcn_readfirstlane((int)x0f);
        int c1 = min(c0 + 1, WF - 1);

        if (c0 == ccol) {
            pcol = ccol; vap = vac; vbp = vbc;
            loadcol<RC>(pbase, c1, ro0, ro1, ro2, ro3, wya, wyb, vac, vbc);
            ccol = c1;
        } else if (c0 != pcol) {
            loadcol<RC>(pbase, c0, ro0, ro1, ro2, ro3, wya, wyb, vap, vbp);
            pcol = c0;
            loadcol<RC>(pbase, c1, ro0, ro1, ro2, ro3, wya, wyb, vac, vbc);
            ccol = c1;
        }

        float4 sa = lerp4(vap, vac, wx);
        float4 sb = lerp4(vbp, vbc, wx);
        float4 mm = max4(sa, sb);
        m0 = max4(m0, mm);

        if (sx & 1) {
            store_nt4(obase + (size_t)(sx >> 1) * CC, m0);
            m0 = make_float4(-INFINITY, -INFINITY, -INFINITY, -INFINITY);
        }
    }
}

// One block per (roi, pooled_row). 128 threads * float4 = 512 channels.
__global__ __launch_bounds__(128, 4) void roipool_kernel(
    const float* __restrict__ feat,    // [HF, WF, CC]
    const float* __restrict__ rois,    // [N, 4] (x1,y1,x2,y2)
    const int*   __restrict__ im_size, // [2] (h, w)
    float*       __restrict__ out,     // [N, 7, 7, CC]
    int N)
{
    int bid = blockIdx.x;
    int n   = bid / POOLD;
    int py  = bid - n * POOLD;
    if (n >= N) return;

    float h = (float)im_size[0];
    float w = (float)im_size[1];
    float bx1 = rois[4 * n + 0];
    float by1 = rois[4 * n + 1];
    float bx2 = rois[4 * n + 2];
    float by2 = rois[4 * n + 3];
    float ny1 = by1 / h, nx1 = bx1 / w;
    float ny2 = by2 / h, nx2 = bx2 / w;

    const float inv = 1.0f / (float)(SAMPD - 1);

    // vertical taps for the two sample rows of this pooled row (block-uniform)
    float tya = (float)(2 * py) * inv;
    float tyb = (float)(2 * py + 1) * inv;
    float ysa = (ny1 + (ny2 - ny1) * tya) * (float)(HF - 1);
    float ysb = (ny1 + (ny2 - ny1) * tyb) * (float)(HF - 1);
    ysa = fminf(fmaxf(ysa, 0.0f), (float)(HF - 1));
    ysb = fminf(fmaxf(ysb, 0.0f), (float)(HF - 1));
    float y0fa = floorf(ysa);
    float y0fb = floorf(ysb);
    float wya = ysa - y0fa;
    float wyb = ysb - y0fb;
    int iya = __builtin_amdgcn_readfirstlane((int)y0fa);
    int iyb = __builtin_amdgcn_readfirstlane((int)y0fb);
    int iya1 = min(iya + 1, HF - 1);
    int iyb1 = min(iyb + 1, HF - 1);
    int ro0 = iya  * (WF * CC);
    int ro1 = iya1 * (WF * CC);
    int ro2 = iyb  * (WF * CC);
    int ro3 = iyb1 * (WF * CC);

    const float* pbase = feat + (size_t)threadIdx.x * 4;
    float* obase = out + ((size_t)(n * POOLD + py) * POOLD) * CC + (size_t)threadIdx.x * 4;

    // Row-sharing case is fixed for the whole block -> one scalar dispatch.
    if (ro2 == ro0) {
        run_row<0>(pbase, obase, nx1, nx2, ro0, ro1, ro2, ro3, wya, wyb);
    } else if (ro2 == ro1) {
        run_row<1>(pbase, obase, nx1, nx2, ro0, ro1, ro2, ro3, wya, wyb);
    } else {
        run_row<2>(pbase, obase, nx1, nx2, ro0, ro1, ro2, ro3, wya, wyb);
    }
}

extern "C" void kernel_launch(void* const* d_in, const int* in_sizes, int n_in,
                              void* d_out, int out_size, void* d_ws, size_t ws_size,
                              hipStream_t stream) {
    const float* feat    = (const float*)d_in[0];   // [1,37,50,512]
    const float* rois    = (const float*)d_in[1];   // [N,4]
    const int*   im_size = (const int*)d_in[2];     // [2]
    float* out = (float*)d_out;

    int N = in_sizes[1] / 4;
    int nblocks = N * POOLD;
    roipool_kernel<<<nblocks, 128, 0, stream>>>(feat, rois, im_size, out, N);
}